// Round 8
// baseline (149.240 us; speedup 1.0000x reference)
//
#include <hip/hip_runtime.h>
#include <math.h>

#define N_TRIAL 1000000
#define N_STIM 10000
#define N_REF 8
#define N_DIM 16
#define N_GROUP 4
#define BETA 1.0f
#define GAMMA 0.001f
// N_SELECT = {1,2,3,1} packed as nibbles
#define N_SELECT_PACKED 0x1321

#define WPB 4          // waves per block
#define D2_STRIDE 72   // 64+8: write banks (16s+q)%32 and read banks (8r+lane)%32 both 2-way = free

typedef float v4f __attribute__((ext_vector_type(4)));

// ---------------------------------------------------------------------------
// Kernel 1: fp32 embed -> bf16 (RNE) table in workspace. 160k elems, ~3 us.
// ---------------------------------------------------------------------------
__global__ __launch_bounds__(256) void convert_kernel(
    const float* __restrict__ embed, unsigned int* __restrict__ ebf)
{
    int i = blockIdx.x * 256 + threadIdx.x;      // one packed uint (2 elems)/thread
    if (i >= N_STIM * N_DIM / 2) return;
    unsigned int b0 = __builtin_bit_cast(unsigned int, embed[2 * i]);
    unsigned int b1 = __builtin_bit_cast(unsigned int, embed[2 * i + 1]);
    b0 = (b0 + 0x7fffu + ((b0 >> 16) & 1u)) >> 16;   // RNE to bf16
    b1 = (b1 + 0x7fffu + ((b1 >> 16) & 1u)) >> 16;
    ebf[i] = b0 | (b1 << 16);
}

__device__ __forceinline__ v4f bf16x4_to_f32(unsigned long long u64) {
    unsigned int lo = (unsigned int)u64;
    unsigned int hi = (unsigned int)(u64 >> 32);
    v4f z;
    z.x = __builtin_bit_cast(float, lo << 16);
    z.y = __builtin_bit_cast(float, lo & 0xffff0000u);
    z.z = __builtin_bit_cast(float, hi << 16);
    z.w = __builtin_bit_cast(float, hi & 0xffff0000u);
    return z;
}

// ---------------------------------------------------------------------------
// Kernel 2: round-5 structure, bf16 gathers via agent-scope (sc0) loads that
// BYPASS L1. Rounds 3-7 showed an occupancy- and byte-independent wall at
// ~0.26 lines/cyc/CU: line-granular L1 fills on ~95%-miss random gathers
// (9e6 x 64 B = 576 MB L2->L1 fill regardless of dtype). sc0 loads return
// data from L2 without allocating L1 lines -- no fill-port serialization.
// Atomic loads also pin program order, so the 9-load batch per pass actually
// stays batched (round 6's pipeline was re-sunk by the compiler).
// ---------------------------------------------------------------------------
__global__ __launch_bounds__(256) void likelihood_kernel(
    const int* __restrict__ stim,     // N_TRIAL x 9
    const int* __restrict__ config,   // N_TRIAL
    const int* __restrict__ group,    // N_TRIAL
    const int* __restrict__ present,  // N_TRIAL x 9
    const unsigned long long* __restrict__ ebf,  // N_STIM x 16 bf16 = 4 u64/row
    const float* __restrict__ attw,   // N_GROUP x 16
    float* __restrict__ out)          // N_TRIAL
{
    __shared__ int4  s_stim4[WPB][144];            // 64 trials x 9 ints, dense
    __shared__ int4  s_pres4[WPB][144];            // same for present
    __shared__ float s_d2[WPB][N_REF][D2_STRIDE];  // [ref][trial] transpose

    const int tid  = threadIdx.x;
    const int wv   = tid >> 6;
    const int lane = tid & 63;
    const int q    = lane >> 2;   // quad id 0..15
    const int s    = lane & 3;    // bf16x4 segment 0..3

    int wtb = blockIdx.x * 256 + wv * 64;          // this wave's 64 trials
    const bool valid = (wtb + lane) < N_TRIAL;
    if (wtb > N_TRIAL - 64) wtb = N_TRIAL - 64;    // clamp (N_TRIAL % 64 == 0)

    // ---- dense coalesced staging: each stream cache line touched ONCE ----
    {
        const int4* g4 = (const int4*)(stim + wtb * 9);      // 144 int4/wave
        s_stim4[wv][lane]      = g4[lane];
        s_stim4[wv][64 + lane] = g4[64 + lane];
        if (lane < 16) s_stim4[wv][128 + lane] = g4[128 + lane];
        const int4* p4 = (const int4*)(present + wtb * 9);
        s_pres4[wv][lane]      = p4[lane];
        s_pres4[wv][64 + lane] = p4[64 + lane];
        if (lane < 16) s_pres4[wv][128 + lane] = p4[128 + lane];
    }

    const int t2 = wtb + lane;                     // phase-2 trial
    int c    = config[t2];
    int gall = group[t2];                          // redistributed via __shfl

    const int* stim_lds = (const int*)&s_stim4[wv][0];

    // ---------------- Phase 1: quad layout, 4 passes x 16 trials ----------
    for (int j = 0; j < 4; ++j) {
        const int* sp = stim_lds + (16 * j + q) * 9;
        int idx[9];
#pragma unroll
        for (int i = 0; i < 9; ++i) idx[i] = sp[i];   // 2-way banks = free

        // batch ALL 9 gathers as agent-scope (sc0, L1-bypass) 8-B loads;
        // atomic program order keeps them issued back-to-back before use
        unsigned long long zraw[9];
#pragma unroll
        for (int i = 0; i < 9; ++i)
            zraw[i] = __hip_atomic_load(ebf + (idx[i] * 4 + s),
                                        __ATOMIC_RELAXED,
                                        __HIP_MEMORY_SCOPE_AGENT);

        int g  = __shfl(gall, 16 * j + q);            // quad-uniform group id
        v4f w  = *(const v4f*)(attw + g * N_DIM + s * 4);   // 256 B, L1-hot
        v4f zq = bf16x4_to_f32(zraw[0]);

        float d2v[N_REF];
#pragma unroll
        for (int r = 0; r < N_REF; ++r) {
            v4f zr = bf16x4_to_f32(zraw[1 + r]);
            v4f dd = zq - zr;
            v4f wd = w * dd;
            float d2 = (wd.x * dd.x + wd.y * dd.y) + (wd.z * dd.z + wd.w * dd.w);
            d2 += __shfl_xor(d2, 1);   // quad butterfly: full 16-dim sum
            d2 += __shfl_xor(d2, 2);
            d2v[r] = d2;
        }
        // lane s persists rows 2s, 2s+1 (uses the quad replication)
        float da = (s == 0) ? d2v[0] : (s == 1) ? d2v[2] : (s == 2) ? d2v[4] : d2v[6];
        float db = (s == 0) ? d2v[1] : (s == 1) ? d2v[3] : (s == 2) ? d2v[5] : d2v[7];
        s_d2[wv][2 * s    ][16 * j + q] = da;
        s_d2[wv][2 * s + 1][16 * j + q] = db;
    }
    // intra-wave ds_write -> ds_read ordering via compiler lgkmcnt; no barrier

    // ---------------- Phase 2: thread-per-trial tail -----------------------
    const int* pres_lds = (const int*)&s_pres4[wv][0] + lane * 9;  // stride 9: 2-way = free

    float sim[N_REF];
#pragma unroll
    for (int r = 0; r < N_REF; ++r) {
        float d2 = s_d2[wv][r][lane];
        sim[r] = (__expf(-BETA * sqrtf(d2)) + GAMMA) * (float)pres_lds[1 + r];
    }

    int ns = (N_SELECT_PACKED >> ((c & 3) * 4)) & 0xF;   // ns in {1,2,3}

    // only suffix[0..2] can be selected (max N_SELECT == 3)
    float suf2 = sim[7];
#pragma unroll
    for (int r = 6; r >= 2; --r) suf2 += sim[r];
    float suf1 = suf2 + sim[1];
    float suf0 = suf1 + sim[0];

    float num = sim[0] * ((ns >= 2) ? sim[1] : 1.0f) * ((ns >= 3) ? sim[2] : 1.0f);
    float den = suf0   * ((ns >= 2) ? suf1   : 1.0f) * ((ns >= 3) ? suf2   : 1.0f);

    if (valid)
        out[wtb + lane] = __fdividef(num, den);   // fully coalesced store
}

extern "C" void kernel_launch(void* const* d_in, const int* in_sizes, int n_in,
                              void* d_out, int out_size, void* d_ws, size_t ws_size,
                              hipStream_t stream) {
    const int*   stim    = (const int*)d_in[0];
    const int*   config  = (const int*)d_in[1];
    const int*   group   = (const int*)d_in[2];
    const int*   present = (const int*)d_in[3];
    const float* embed   = (const float*)d_in[4];
    const float* attw    = (const float*)d_in[5];
    float*       out     = (float*)d_out;

    unsigned int* ebf = (unsigned int*)d_ws;   // N_STIM*N_DIM*2 = 320,000 B

    int cblocks = (N_STIM * N_DIM / 2 + 255) / 256;
    convert_kernel<<<cblocks, 256, 0, stream>>>(embed, ebf);

    int blocks = (N_TRIAL + 255) / 256;   // 3907; tail handled by clamp+valid
    likelihood_kernel<<<blocks, 256, 0, stream>>>(stim, config, group, present,
                                                  (const unsigned long long*)ebf,
                                                  attw, out);
}